// Round 1
// baseline (127.612 us; speedup 1.0000x reference)
//
#include <hip/hip_runtime.h>

#define NN 1024
#define MM 1024
#define DD 256

typedef float floatx2 __attribute__((ext_vector_type(2)));

__device__ __forceinline__ float rcp_fast(float x) { return __builtin_amdgcn_rcpf(x); }

// ---------------- K1: fused dual GEMM + exp epilogue (unchanged) ----------------
// blocks 0..127:   q = f_r @ W_w^T + W_b    -> Eq[n][d]  = exp(2q)   (clamped +-5)
// blocks 128..255: k = f_rp @ Wp_w^T + Wp_b -> EkT[d][m] = exp(2k)   (LDS-transposed)
// Block 0 also zeroes d_out for K3b's atomicAdd.
__global__ __launch_bounds__(256) void gemm_exp_kernel(
    const float* __restrict__ f_r,  const float* __restrict__ W_w,  const float* __restrict__ W_b,
    const float* __restrict__ f_rp, const float* __restrict__ Wp_w, const float* __restrict__ Wp_b,
    float* __restrict__ Eq, float* __restrict__ EkT, float* __restrict__ out0)
{
    __shared__ float As[32][36];   // [k][r]
    __shared__ float Bs[32][68];   // [k][d]
    __shared__ float T[64][36];    // k-path transpose buffer [d_local][r_local]

    const int b = blockIdx.x;
    const int t = threadIdx.x;
    if (b == 0) out0[t] = 0.f;     // zero d_out (256 floats)

    const int mat  = b >> 7;
    const int tile = b & 127;
    const int rt = tile & 31, dt = tile >> 5;
    const float* __restrict__ A    = mat ? f_rp : f_r;
    const float* __restrict__ B    = mat ? Wp_w : W_w;
    const float* __restrict__ bias = mat ? Wp_b : W_b;

    const int tx = t & 15, ty = t >> 4;          // tx -> 4 d-cols, ty -> 2 r-rows
    const int r0 = rt * 32, d0 = dt * 64;
    const int ar = t >> 3, ak = (t & 7) * 4;     // A stage: 32 rows x 32 k
    const int br = t >> 2, bk = (t & 3) * 8;     // B stage: 64 rows x 32 k

    float acc[2][4];
    #pragma unroll
    for (int i = 0; i < 2; ++i)
        #pragma unroll
        for (int j = 0; j < 4; ++j) acc[i][j] = 0.f;

    for (int kk = 0; kk < DD; kk += 32) {
        float4 av  = *(const float4*)(A + (size_t)(r0 + ar) * DD + kk + ak);
        float4 bv0 = *(const float4*)(B + (size_t)(d0 + br) * DD + kk + bk);
        float4 bv1 = *(const float4*)(B + (size_t)(d0 + br) * DD + kk + bk + 4);
        __syncthreads();
        As[ak + 0][ar] = av.x; As[ak + 1][ar] = av.y; As[ak + 2][ar] = av.z; As[ak + 3][ar] = av.w;
        Bs[bk + 0][br] = bv0.x; Bs[bk + 1][br] = bv0.y; Bs[bk + 2][br] = bv0.z; Bs[bk + 3][br] = bv0.w;
        Bs[bk + 4][br] = bv1.x; Bs[bk + 5][br] = bv1.y; Bs[bk + 6][br] = bv1.z; Bs[bk + 7][br] = bv1.w;
        __syncthreads();
        #pragma unroll
        for (int k = 0; k < 32; ++k) {
            float2 a2 = *(const float2*)&As[k][ty * 2];
            float4 b4 = *(const float4*)&Bs[k][tx * 4];
            float aa[2] = {a2.x, a2.y};
            float bb[4] = {b4.x, b4.y, b4.z, b4.w};
            #pragma unroll
            for (int i = 0; i < 2; ++i)
                #pragma unroll
                for (int j = 0; j < 4; ++j)
                    acc[i][j] = fmaf(aa[i], bb[j], acc[i][j]);
        }
    }

    float bj[4];
    #pragma unroll
    for (int j = 0; j < 4; ++j) bj[j] = bias[d0 + tx * 4 + j];

    float e[2][4];
    #pragma unroll
    for (int i = 0; i < 2; ++i)
        #pragma unroll
        for (int j = 0; j < 4; ++j) {
            float v = acc[i][j] + bj[j];
            // +-5: tanh(5)=0.9999092 (error 9e-5, negligible after w-weighting);
            // also bounds the no-max exp in K2: |s~| <= 2*sum|w| <= 32 -> e^32 << fp32 max.
            v = fminf(fmaxf(v, -5.f), 5.f);
            e[i][j] = __expf(2.f * v);
        }

    if (mat == 0) {
        #pragma unroll
        for (int i = 0; i < 2; ++i)
            *(float4*)&Eq[(size_t)(r0 + ty * 2 + i) * DD + d0 + tx * 4] =
                make_float4(e[i][0], e[i][1], e[i][2], e[i][3]);
    } else {
        __syncthreads();
        #pragma unroll
        for (int i = 0; i < 2; ++i)
            #pragma unroll
            for (int j = 0; j < 4; ++j) T[tx * 4 + j][ty * 2 + i] = e[i][j];
        __syncthreads();
        const int dl = t >> 3, rl = (t & 7) * 4;
        #pragma unroll
        for (int h = 0; h < 2; ++h) {
            int dloc = dl + 32 * h;
            float4 tv = *(const float4*)&T[dloc][rl];
            *(float4*)&EkT[(size_t)(d0 + dloc) * MM + r0 + rl] = tv;
        }
    }
}

// ---------------- K2': m-split mega kernel ----------------
// 512 blocks x 1024 thr; block = (n-quad = bid>>1, m-half = bid&1).
// 2 blocks/CU (LDS 73.8KB, VGPR<=64) -> 32 waves/CU for latency hiding.
// Phase A: tg = d-quarter; tm -> 2 m-cols. s~[n,m] = -2 sum_d w_d/(Eq*Ek+1),
//   4-way rcp combining, pk-packed, q/w via wave-uniform scalar loads.
// Phase B: NO-MAX exp (scores provably bounded |s~|<=32): e = exp(s~),
//   partial denominator S_half[n] -> global; e -> LDS.
// Phase C: ctx~_half = e @ frp[m-half] (unnormalized partial context) -> global.
// Cross-half combine + normalize deferred to K3a (deterministic, no atomics).
__global__ __launch_bounds__(1024, 8) void fused_attn_kernel(
    const float* __restrict__ Eq, const float* __restrict__ EkT,
    const float* __restrict__ w_w, const float* __restrict__ frp,
    float* __restrict__ ctxA, float* __restrict__ ctxB,
    float* __restrict__ SpA, float* __restrict__ SpB)
{
    // union region: accbuf (phase A->B) aliases ctxred (phase C); lifetimes
    // separated by the phase-B __syncthreads.
    __shared__ __align__(16) char usm_raw[65536];
    float2 (*accbuf)[4][256] = (float2 (*)[4][256])(void*)usm_raw;  // [4][4][256] 32KB
    float4 (*ctxred)[4][64]  = (float4 (*)[4][64])(void*)usm_raw;   // [16][4][64] 64KB
    __shared__ float alsm[4][512];   // 8KB unnormalized e
    __shared__ float redsm[4][4];

    const int t  = threadIdx.x;
    const int tg = t >> 8;        // d-quarter
    const int tm = t & 255;       // m-cols m0+2tm, m0+2tm+1
    const int bm = blockIdx.x & 1;
    const int n0 = (blockIdx.x >> 1) * 4;
    const int m0 = bm * 512;

    // wave-uniform scalar bases (tg constant within a wave)
    const int dh = __builtin_amdgcn_readfirstlane(tg * 64);
    const float* __restrict__ eqb = Eq + (size_t)n0 * DD + dh;
    const float* __restrict__ wwb = w_w + dh;

    // ---- Phase A: scores over d-quarter ----
    const floatx2 one2 = {1.f, 1.f};
    floatx2 acc2[4] = {{0.f,0.f},{0.f,0.f},{0.f,0.f},{0.f,0.f}};

    const float* ekb = EkT + (size_t)dh * MM + m0 + 2 * tm;
    float2 c0 = *(const float2*)(ekb + 0 * MM);
    float2 c1 = *(const float2*)(ekb + 1 * MM);
    float2 c2 = *(const float2*)(ekb + 2 * MM);
    float2 c3 = *(const float2*)(ekb + 3 * MM);

    for (int gi = 0; gi < 16; ++gi) {
        float2 p0 = c0, p1 = c1, p2 = c2, p3 = c3;
        if (gi < 15) {
            const float* nb = ekb + (size_t)(gi * 4 + 4) * MM;
            p0 = *(const float2*)(nb + 0 * MM);
            p1 = *(const float2*)(nb + 1 * MM);
            p2 = *(const float2*)(nb + 2 * MM);
            p3 = *(const float2*)(nb + 3 * MM);
        }
        const int db = gi * 4;
        float4 w4 = *(const float4*)(wwb + db);            // scalar (uniform)
        floatx2 kv0 = {c0.x, c0.y}, kv1 = {c1.x, c1.y};
        floatx2 kv2 = {c2.x, c2.y}, kv3 = {c3.x, c3.y};
        #pragma unroll
        for (int n = 0; n < 4; ++n) {
            float4 q4 = *(const float4*)(eqb + n * DD + db);   // scalar (uniform)
            floatx2 x0 = q4.x * kv0 + one2;
            floatx2 x1 = q4.y * kv1 + one2;
            floatx2 x2 = q4.z * kv2 + one2;
            floatx2 x3 = q4.w * kv3 + one2;
            floatx2 p01 = x0 * x1;
            floatx2 p23 = x2 * x3;
            floatx2 n01 = w4.x * x1 + w4.y * x0;
            floatx2 n23 = w4.z * x3 + w4.w * x2;
            floatx2 nc  = n01 * p23 + n23 * p01;
            floatx2 pt  = p01 * p23;
            floatx2 r;  r.x = rcp_fast(pt.x);  r.y = rcp_fast(pt.y);
            acc2[n] += nc * r;
        }
        c0 = p0; c1 = p1; c2 = p2; c3 = p3;
    }

    #pragma unroll
    for (int n = 0; n < 4; ++n)
        accbuf[tg][n][tm] = make_float2(-2.f * acc2[n].x, -2.f * acc2[n].y);
    __syncthreads();

    // ---- Phase B: all-tg combine + no-max exp; tg g owns row g ----
    const int g = tg;
    const int w4id = (t >> 6) & 3;
    const int lane = t & 63;
    float2 a0 = accbuf[0][g][tm], a1 = accbuf[1][g][tm];
    float2 a2 = accbuf[2][g][tm], a3 = accbuf[3][g][tm];
    float sx = a0.x + a1.x + a2.x + a3.x;
    float sy = a0.y + a1.y + a2.y + a3.y;
    float ex = __expf(sx), ey = __expf(sy);          // bounded: |s~| <= 32
    *(float2*)&alsm[g][2 * tm] = make_float2(ex, ey);
    float sm = ex + ey;
    #pragma unroll
    for (int off = 32; off > 0; off >>= 1) sm += __shfl_xor(sm, off);
    if (lane == 0) redsm[g][w4id] = sm;
    __syncthreads();   // alsm+redsm ready; accbuf dead -> ctxred alias safe
    if (tm == 0) {
        float* Sp = bm ? SpB : SpA;
        Sp[n0 + g] = redsm[g][0] + redsm[g][1] + redsm[g][2] + redsm[g][3];
    }

    // ---- Phase C: ctx~ = e @ frp over this m-half (m-range split) ----
    const int cc = t & 63;        // d-cols 4cc..4cc+3
    const int rr = t >> 6;        // m-range rr*32 .. +31 (local)
    floatx2 axl[4] = {{0.f,0.f},{0.f,0.f},{0.f,0.f},{0.f,0.f}};
    floatx2 axh[4] = {{0.f,0.f},{0.f,0.f},{0.f,0.f},{0.f,0.f}};
    const float* fb = frp + (size_t)(m0 + rr * 32) * DD + 4 * cc;
    for (int m8 = 0; m8 < 8; ++m8) {
        float alv[4][4];
        #pragma unroll
        for (int n = 0; n < 4; ++n) {
            float4 a4 = *(const float4*)&alsm[n][rr * 32 + m8 * 4];
            alv[n][0] = a4.x; alv[n][1] = a4.y; alv[n][2] = a4.z; alv[n][3] = a4.w;
        }
        #pragma unroll
        for (int mm = 0; mm < 4; ++mm) {
            float4 f = *(const float4*)(fb + (size_t)(m8 * 4 + mm) * DD);
            floatx2 fl = {f.x, f.y}, fh = {f.z, f.w};
            #pragma unroll
            for (int n = 0; n < 4; ++n) {
                axl[n] += alv[n][mm] * fl;
                axh[n] += alv[n][mm] * fh;
            }
        }
    }
    #pragma unroll
    for (int n = 0; n < 4; ++n)
        ctxred[rr][n][cc] = make_float4(axl[n].x, axl[n].y, axh[n].x, axh[n].y);
    __syncthreads();

    // final range-reduce: thread t -> (n = t>>8, d = t&255)
    const int nn = t >> 8, d = t & 255;
    float s = 0.f;
    #pragma unroll
    for (int r = 0; r < 16; ++r)
        s += ((const float*)&ctxred[r][nn][d >> 2])[d & 3];
    float* ctxP = bm ? ctxB : ctxA;
    ctxP[(size_t)(n0 + nn) * DD + d] = s;
}

// ---------------- K3a: half-combine + normalize + stage-2 score ----------------
// 256 blocks x 256 thr; block b -> rows 4b..4b+3 (wave per row, 4 d-cols/lane).
__global__ __launch_bounds__(256) void combine_kernel(
    const float* __restrict__ ctxA, const float* __restrict__ ctxB,
    const float* __restrict__ SpA, const float* __restrict__ SpB,
    const float* __restrict__ wp_w,
    float* __restrict__ ctx, float* __restrict__ score)
{
    const int t = threadIdx.x, lane = t & 63;
    const int row = blockIdx.x * 4 + (t >> 6);
    const float inv = rcp_fast(SpA[row] + SpB[row]);
    const size_t off = (size_t)row * DD + 4 * lane;
    float4 a = *(const float4*)(ctxA + off);
    float4 b = *(const float4*)(ctxB + off);
    float4 c = make_float4((a.x + b.x) * inv, (a.y + b.y) * inv,
                           (a.z + b.z) * inv, (a.w + b.w) * inv);
    *(float4*)(ctx + off) = c;
    float4 w = *(const float4*)(wp_w + 4 * lane);
    float p = c.x * w.x + c.y * w.y + c.z * w.z + c.w * w.w;
    #pragma unroll
    for (int o = 32; o > 0; o >>= 1) p += __shfl_xor(p, o);
    if (lane == 0) score[row] = p;
}

// ---------------- K3b: softmax over N (redundant per block) + pooled sum ----------------
__global__ __launch_bounds__(256) void pool_kernel(
    const float* __restrict__ ctx, const float* __restrict__ score,
    float* __restrict__ out)
{
    __shared__ float red[8];
    const int t = threadIdx.x, lane = t & 63, wid = t >> 6;
    const int n0 = blockIdx.x * 4;

    float s0 = score[t], s1 = score[t + 256], s2 = score[t + 512], s3 = score[t + 768];
    float mx = fmaxf(fmaxf(s0, s1), fmaxf(s2, s3));
    #pragma unroll
    for (int off = 32; off > 0; off >>= 1) mx = fmaxf(mx, __shfl_xor(mx, off));
    if (lane == 0) red[wid] = mx;
    __syncthreads();
    mx = fmaxf(fmaxf(red[0], red[1]), fmaxf(red[2], red[3]));

    float se = __expf(s0 - mx) + __expf(s1 - mx) + __expf(s2 - mx) + __expf(s3 - mx);
    #pragma unroll
    for (int off = 32; off > 0; off >>= 1) se += __shfl_xor(se, off);
    if (lane == 0) red[4 + wid] = se;
    __syncthreads();
    se = red[4] + red[5] + red[6] + red[7];
    float invS = rcp_fast(se);

    float r = 0.f;
    #pragma unroll
    for (int i = 0; i < 4; ++i) {
        float ap = __expf(score[n0 + i] - mx) * invS;   // wave-uniform broadcast load
        r = fmaf(ap, ctx[(size_t)(n0 + i) * DD + t], r);
    }
    atomicAdd(out + t, r);
}

extern "C" void kernel_launch(void* const* d_in, const int* in_sizes, int n_in,
                              void* d_out, int out_size, void* d_ws, size_t ws_size,
                              hipStream_t stream) {
    const float* f_r  = (const float*)d_in[0];
    const float* f_rp = (const float*)d_in[1];
    const float* W_w  = (const float*)d_in[2];
    const float* W_b  = (const float*)d_in[3];
    const float* Wp_w = (const float*)d_in[4];
    const float* Wp_b = (const float*)d_in[5];
    const float* w_w  = (const float*)d_in[6];
    // d_in[7] = w_b  : cancels in softmax over m
    const float* wp_w = (const float*)d_in[8];
    // d_in[9] = wp_b : cancels in softmax over n
    float* out = (float*)d_out;

    float* ws    = (float*)d_ws;
    float* Eq    = ws;                  // 256K floats
    float* EkT   = ws + 262144;         // 256K
    float* ctxA  = ws + 524288;         // 256K (unnormalized half-0 context)
    float* ctxB  = ws + 786432;         // 256K (unnormalized half-1 context)
    float* ctxn  = ws + 1048576;        // 256K (normalized context)
    float* SpA   = ws + 1310720;        // 1K (half-0 softmax denominators)
    float* SpB   = ws + 1311744;        // 1K
    float* score = ws + 1312768;        // 1K

    gemm_exp_kernel<<<256, 256, 0, stream>>>(f_r, W_w, W_b, f_rp, Wp_w, Wp_b, Eq, EkT, out);
    fused_attn_kernel<<<512, 1024, 0, stream>>>(Eq, EkT, w_w, f_rp, ctxA, ctxB, SpA, SpB);
    combine_kernel<<<256, 256, 0, stream>>>(ctxA, ctxB, SpA, SpB, wp_w, ctxn, score);
    pool_kernel<<<256, 256, 0, stream>>>(ctxn, score, out);
}

// Round 2
// 122.663 us; speedup vs baseline: 1.0403x; 1.0403x over previous
//
#include <hip/hip_runtime.h>

#define NN 1024
#define MM 1024
#define DD 256

typedef float floatx2 __attribute__((ext_vector_type(2)));

__device__ __forceinline__ float rcp_fast(float x) { return __builtin_amdgcn_rcpf(x); }

// ---------------- K1: fused dual GEMM + exp epilogue (unchanged) ----------------
// blocks 0..127:   q = f_r @ W_w^T + W_b    -> Eq[n][d]  = exp(2q)   (clamped +-5)
// blocks 128..255: k = f_rp @ Wp_w^T + Wp_b -> EkT[d][m] = exp(2k)   (LDS-transposed)
// Block 0 also zeroes d_out for K3's atomicAdd.
__global__ __launch_bounds__(256) void gemm_exp_kernel(
    const float* __restrict__ f_r,  const float* __restrict__ W_w,  const float* __restrict__ W_b,
    const float* __restrict__ f_rp, const float* __restrict__ Wp_w, const float* __restrict__ Wp_b,
    float* __restrict__ Eq, float* __restrict__ EkT, float* __restrict__ out0)
{
    __shared__ float As[32][36];   // [k][r]
    __shared__ float Bs[32][68];   // [k][d]
    __shared__ float T[64][36];    // k-path transpose buffer [d_local][r_local]

    const int b = blockIdx.x;
    const int t = threadIdx.x;
    if (b == 0) out0[t] = 0.f;     // zero d_out (256 floats)

    const int mat  = b >> 7;
    const int tile = b & 127;
    const int rt = tile & 31, dt = tile >> 5;
    const float* __restrict__ A    = mat ? f_rp : f_r;
    const float* __restrict__ B    = mat ? Wp_w : W_w;
    const float* __restrict__ bias = mat ? Wp_b : W_b;

    const int tx = t & 15, ty = t >> 4;          // tx -> 4 d-cols, ty -> 2 r-rows
    const int r0 = rt * 32, d0 = dt * 64;
    const int ar = t >> 3, ak = (t & 7) * 4;     // A stage: 32 rows x 32 k
    const int br = t >> 2, bk = (t & 3) * 8;     // B stage: 64 rows x 32 k

    float acc[2][4];
    #pragma unroll
    for (int i = 0; i < 2; ++i)
        #pragma unroll
        for (int j = 0; j < 4; ++j) acc[i][j] = 0.f;

    for (int kk = 0; kk < DD; kk += 32) {
        float4 av  = *(const float4*)(A + (size_t)(r0 + ar) * DD + kk + ak);
        float4 bv0 = *(const float4*)(B + (size_t)(d0 + br) * DD + kk + bk);
        float4 bv1 = *(const float4*)(B + (size_t)(d0 + br) * DD + kk + bk + 4);
        __syncthreads();
        As[ak + 0][ar] = av.x; As[ak + 1][ar] = av.y; As[ak + 2][ar] = av.z; As[ak + 3][ar] = av.w;
        Bs[bk + 0][br] = bv0.x; Bs[bk + 1][br] = bv0.y; Bs[bk + 2][br] = bv0.z; Bs[bk + 3][br] = bv0.w;
        Bs[bk + 4][br] = bv1.x; Bs[bk + 5][br] = bv1.y; Bs[bk + 6][br] = bv1.z; Bs[bk + 7][br] = bv1.w;
        __syncthreads();
        #pragma unroll
        for (int k = 0; k < 32; ++k) {
            float2 a2 = *(const float2*)&As[k][ty * 2];
            float4 b4 = *(const float4*)&Bs[k][tx * 4];
            float aa[2] = {a2.x, a2.y};
            float bb[4] = {b4.x, b4.y, b4.z, b4.w};
            #pragma unroll
            for (int i = 0; i < 2; ++i)
                #pragma unroll
                for (int j = 0; j < 4; ++j)
                    acc[i][j] = fmaf(aa[i], bb[j], acc[i][j]);
        }
    }

    float bj[4];
    #pragma unroll
    for (int j = 0; j < 4; ++j) bj[j] = bias[d0 + tx * 4 + j];

    float e[2][4];
    #pragma unroll
    for (int i = 0; i < 2; ++i)
        #pragma unroll
        for (int j = 0; j < 4; ++j) {
            float v = acc[i][j] + bj[j];
            // +-5: tanh(5)=0.9999092 (error 9e-5, negligible after w-weighting);
            // also bounds the no-max exp in K2: |s~| <= 2*sum|w| <= 32 -> e^32 << fp32 max.
            v = fminf(fmaxf(v, -5.f), 5.f);
            e[i][j] = __expf(2.f * v);
        }

    if (mat == 0) {
        #pragma unroll
        for (int i = 0; i < 2; ++i)
            *(float4*)&Eq[(size_t)(r0 + ty * 2 + i) * DD + d0 + tx * 4] =
                make_float4(e[i][0], e[i][1], e[i][2], e[i][3]);
    } else {
        __syncthreads();
        #pragma unroll
        for (int i = 0; i < 2; ++i)
            #pragma unroll
            for (int j = 0; j < 4; ++j) T[tx * 4 + j][ty * 2 + i] = e[i][j];
        __syncthreads();
        const int dl = t >> 3, rl = (t & 7) * 4;
        #pragma unroll
        for (int h = 0; h < 2; ++h) {
            int dloc = dl + 32 * h;
            float4 tv = *(const float4*)&T[dloc][rl];
            *(float4*)&EkT[(size_t)(d0 + dloc) * MM + r0 + rl] = tv;
        }
    }
}

// ---------------- K2: m-split mega kernel, 4 m/thread ----------------
// 512 blocks x 1024 thr; block = (n-quad = bid>>1, m-half = bid&1). 2 blocks/CU.
// Phase A: tg = t>>7 -> d-group of 32; tm = t&127 -> 4 m-cols (float4 EkT loads,
//   half the VMEM instrs / gi-iters / s_loads of the 2-m layout).
//   s~[n,m] = -2 sum_d w_d/(Eq*Ek+1), 4-way rcp combining, q/w scalar loads.
// Phase B: 8-slab combine + NO-MAX exp (|s~|<=32 provably); partial denom -> Sp.
// Phase C: ctx~_half = e @ frp[m-half] -> ctxA/B; NEW: stage-2 partial score
//   s~_half[n] = ctx~_half[n] . wp_w -> sA/sB (replaces the combine kernel).
__global__ __launch_bounds__(1024, 8) void fused_attn_kernel(
    const float* __restrict__ Eq, const float* __restrict__ EkT,
    const float* __restrict__ w_w, const float* __restrict__ frp,
    const float* __restrict__ wp_w,
    float* __restrict__ ctxA, float* __restrict__ ctxB,
    float* __restrict__ SpA, float* __restrict__ SpB,
    float* __restrict__ sA,  float* __restrict__ sB)
{
    // union region: accbuf2 (phase A->B) aliases ctxred (phase C); lifetimes
    // separated by the phase-B barrier.
    __shared__ __align__(16) char usm_raw[65536];
    float2 (*accbuf2)[4][256] = (float2 (*)[4][256])(void*)usm_raw;  // [8][4][256] 64KB
    float4 (*ctxred)[4][64]   = (float4 (*)[4][64])(void*)usm_raw;   // [16][4][64] 64KB
    __shared__ float alsm[4][512];   // 8KB unnormalized e
    __shared__ float redsm[4][4];
    __shared__ float redsc[16];

    const int t  = threadIdx.x;
    const int tg = t >> 7;        // d-group (8 x 32 d)
    const int tm = t & 127;       // m-cols m0+4tm .. +3
    const int bm = blockIdx.x & 1;
    const int n0 = (blockIdx.x >> 1) * 4;
    const int m0 = bm * 512;

    // wave-uniform scalar bases (tg constant within a wave: 128 thr = 2 waves/tg)
    const int dh = __builtin_amdgcn_readfirstlane(tg * 32);
    const float* __restrict__ eqb = Eq + (size_t)n0 * DD + dh;
    const float* __restrict__ wwb = w_w + dh;

    // ---- Phase A: scores over 32-d group, 4 m/thread ----
    const floatx2 one2 = {1.f, 1.f};
    floatx2 accl[4] = {{0.f,0.f},{0.f,0.f},{0.f,0.f},{0.f,0.f}};   // m 4tm..+1 per n
    floatx2 acch[4] = {{0.f,0.f},{0.f,0.f},{0.f,0.f},{0.f,0.f}};   // m 4tm+2..+3 per n

    const float* ekb = EkT + (size_t)dh * MM + m0 + 4 * tm;

    for (int gi = 0; gi < 8; ++gi) {
        const float* nb = ekb + (size_t)(gi * 4) * MM;
        float4 c0 = *(const float4*)(nb + 0 * MM);
        float4 c1 = *(const float4*)(nb + 1 * MM);
        float4 c2 = *(const float4*)(nb + 2 * MM);
        float4 c3 = *(const float4*)(nb + 3 * MM);
        const int db = gi * 4;
        float4 w4 = *(const float4*)(wwb + db);            // scalar (uniform)
        floatx2 kv[4][2] = {{{c0.x, c0.y}, {c0.z, c0.w}},
                            {{c1.x, c1.y}, {c1.z, c1.w}},
                            {{c2.x, c2.y}, {c2.z, c2.w}},
                            {{c3.x, c3.y}, {c3.z, c3.w}}};
        #pragma unroll
        for (int n = 0; n < 4; ++n) {
            float4 q4 = *(const float4*)(eqb + n * DD + db);   // scalar (uniform)
            #pragma unroll
            for (int h = 0; h < 2; ++h) {
                floatx2 x0 = q4.x * kv[0][h] + one2;
                floatx2 x1 = q4.y * kv[1][h] + one2;
                floatx2 x2 = q4.z * kv[2][h] + one2;
                floatx2 x3 = q4.w * kv[3][h] + one2;
                floatx2 p01 = x0 * x1;
                floatx2 p23 = x2 * x3;
                floatx2 n01 = w4.x * x1 + w4.y * x0;
                floatx2 n23 = w4.z * x3 + w4.w * x2;
                floatx2 nc  = n01 * p23 + n23 * p01;
                floatx2 pt  = p01 * p23;
                floatx2 r;  r.x = rcp_fast(pt.x);  r.y = rcp_fast(pt.y);
                if (h == 0) accl[n] += nc * r; else acch[n] += nc * r;
            }
        }
    }

    // m-pair j = 2tm holds m(4tm,4tm+1); j = 2tm+1 holds m(4tm+2,4tm+3)
    #pragma unroll
    for (int n = 0; n < 4; ++n)
        *(float4*)&accbuf2[tg][n][2 * tm] =
            make_float4(accl[n].x, accl[n].y, acch[n].x, acch[n].y);
    __syncthreads();

    // ---- Phase B: 8-slab combine + no-max exp; thread -> (n = t>>8, pair j = t&255) ----
    const int bn = t >> 8, j = t & 255;
    const int w4id = (t >> 6) & 3;
    const int lane = t & 63;
    float2 aj = make_float2(0.f, 0.f);
    #pragma unroll
    for (int g8 = 0; g8 < 8; ++g8) {
        float2 v = accbuf2[g8][bn][j];
        aj.x += v.x; aj.y += v.y;
    }
    float ex = __expf(-2.f * aj.x), ey = __expf(-2.f * aj.y);   // bounded: |s~| <= 32
    *(float2*)&alsm[bn][2 * j] = make_float2(ex, ey);
    float sm = ex + ey;
    #pragma unroll
    for (int off = 32; off > 0; off >>= 1) sm += __shfl_xor(sm, off);
    if (lane == 0) redsm[bn][w4id] = sm;
    __syncthreads();   // alsm+redsm ready; accbuf2 dead -> ctxred alias safe
    if (j == 0) {
        float* Sp = bm ? SpB : SpA;
        Sp[n0 + bn] = redsm[bn][0] + redsm[bn][1] + redsm[bn][2] + redsm[bn][3];
    }

    // ---- Phase C: ctx~ = e @ frp over this m-half (m-range split) ----
    const int cc = t & 63;        // d-cols 4cc..4cc+3
    const int rr = t >> 6;        // m-range rr*32 .. +31 (local)
    floatx2 axl[4] = {{0.f,0.f},{0.f,0.f},{0.f,0.f},{0.f,0.f}};
    floatx2 axh[4] = {{0.f,0.f},{0.f,0.f},{0.f,0.f},{0.f,0.f}};
    const float* fb = frp + (size_t)(m0 + rr * 32) * DD + 4 * cc;
    for (int m8 = 0; m8 < 8; ++m8) {
        float alv[4][4];
        #pragma unroll
        for (int n = 0; n < 4; ++n) {
            float4 a4 = *(const float4*)&alsm[n][rr * 32 + m8 * 4];
            alv[n][0] = a4.x; alv[n][1] = a4.y; alv[n][2] = a4.z; alv[n][3] = a4.w;
        }
        #pragma unroll
        for (int mm = 0; mm < 4; ++mm) {
            float4 f = *(const float4*)(fb + (size_t)(m8 * 4 + mm) * DD);
            floatx2 fl = {f.x, f.y}, fh = {f.z, f.w};
            #pragma unroll
            for (int n = 0; n < 4; ++n) {
                axl[n] += alv[n][mm] * fl;
                axh[n] += alv[n][mm] * fh;
            }
        }
    }
    #pragma unroll
    for (int n = 0; n < 4; ++n)
        ctxred[rr][n][cc] = make_float4(axl[n].x, axl[n].y, axh[n].x, axh[n].y);
    __syncthreads();

    // final range-reduce: thread t -> (n = t>>8, d = t&255)
    const int nn = t >> 8, d = t & 255;
    float s = 0.f;
    #pragma unroll
    for (int r = 0; r < 16; ++r)
        s += ((const float*)&ctxred[r][nn][d >> 2])[d & 3];
    float* ctxP = bm ? ctxB : ctxA;
    ctxP[(size_t)(n0 + nn) * DD + d] = s;

    // stage-2 partial score: s~_half[n] = ctx~_half[n] . wp_w
    float p = s * wp_w[d];
    #pragma unroll
    for (int off = 32; off > 0; off >>= 1) p += __shfl_xor(p, off);
    if (lane == 0) redsc[t >> 6] = p;
    __syncthreads();
    if (t < 4) {
        float* sP = bm ? sB : sA;
        sP[n0 + t] = redsc[4 * t] + redsc[4 * t + 1] + redsc[4 * t + 2] + redsc[4 * t + 3];
    }
}

// ---------------- K3: softmax over N (redundant per block) + pooled sum ----------------
// 256 blocks x 256 thr; block b handles n-rows 4b..4b+3.
// score[row] = (sA+sB)/(SpA+SpB) reconstructed from 4 scalars (combine kernel fused away).
__global__ __launch_bounds__(256) void pool_kernel(
    const float* __restrict__ ctxA, const float* __restrict__ ctxB,
    const float* __restrict__ SpA,  const float* __restrict__ SpB,
    const float* __restrict__ sA,   const float* __restrict__ sB,
    float* __restrict__ out)
{
    __shared__ float red[8];
    const int t = threadIdx.x, lane = t & 63, wid = t >> 6;
    const int n0 = blockIdx.x * 4;

    float sc[4];
    #pragma unroll
    for (int i = 0; i < 4; ++i) {
        int r = t + 256 * i;
        sc[i] = (sA[r] + sB[r]) * rcp_fast(SpA[r] + SpB[r]);
    }
    float mx = fmaxf(fmaxf(sc[0], sc[1]), fmaxf(sc[2], sc[3]));
    #pragma unroll
    for (int off = 32; off > 0; off >>= 1) mx = fmaxf(mx, __shfl_xor(mx, off));
    if (lane == 0) red[wid] = mx;
    __syncthreads();
    mx = fmaxf(fmaxf(red[0], red[1]), fmaxf(red[2], red[3]));

    float se = __expf(sc[0] - mx) + __expf(sc[1] - mx) + __expf(sc[2] - mx) + __expf(sc[3] - mx);
    #pragma unroll
    for (int off = 32; off > 0; off >>= 1) se += __shfl_xor(se, off);
    if (lane == 0) red[4 + wid] = se;
    __syncthreads();
    se = red[4] + red[5] + red[6] + red[7];
    float invS = rcp_fast(se);

    float racc = 0.f;
    #pragma unroll
    for (int i = 0; i < 4; ++i) {
        int row = n0 + i;
        float invRow = rcp_fast(SpA[row] + SpB[row]);      // wave-uniform scalar loads
        float scr = (sA[row] + sB[row]) * invRow;
        float ap = __expf(scr - mx) * invS;
        float cr = (ctxA[(size_t)row * DD + t] + ctxB[(size_t)row * DD + t]) * invRow;
        racc = fmaf(ap, cr, racc);
    }
    atomicAdd(out + t, racc);
}

extern "C" void kernel_launch(void* const* d_in, const int* in_sizes, int n_in,
                              void* d_out, int out_size, void* d_ws, size_t ws_size,
                              hipStream_t stream) {
    const float* f_r  = (const float*)d_in[0];
    const float* f_rp = (const float*)d_in[1];
    const float* W_w  = (const float*)d_in[2];
    const float* W_b  = (const float*)d_in[3];
    const float* Wp_w = (const float*)d_in[4];
    const float* Wp_b = (const float*)d_in[5];
    const float* w_w  = (const float*)d_in[6];
    // d_in[7] = w_b  : cancels in softmax over m
    const float* wp_w = (const float*)d_in[8];
    // d_in[9] = wp_b : cancels in softmax over n
    float* out = (float*)d_out;

    float* ws    = (float*)d_ws;
    float* Eq    = ws;                  // 256K floats
    float* EkT   = ws + 262144;         // 256K
    float* ctxA  = ws + 524288;         // 256K (unnormalized half-0 context)
    float* ctxB  = ws + 786432;         // 256K (unnormalized half-1 context)
    float* SpA   = ws + 1048576;        // 1K (half softmax denominators)
    float* SpB   = ws + 1049600;        // 1K
    float* sA    = ws + 1050624;        // 1K (half stage-2 partial scores)
    float* sB    = ws + 1051648;        // 1K

    gemm_exp_kernel<<<256, 256, 0, stream>>>(f_r, W_w, W_b, f_rp, Wp_w, Wp_b, Eq, EkT, out);
    fused_attn_kernel<<<512, 1024, 0, stream>>>(Eq, EkT, w_w, f_rp, wp_w,
                                                ctxA, ctxB, SpA, SpB, sA, sB);
    pool_kernel<<<256, 256, 0, stream>>>(ctxA, ctxB, SpA, SpB, sA, sB, out);
}